// Round 7
// baseline (46.118 us; speedup 1.0000x reference)
//
#include <hip/hip_runtime.h>
#include <hip/hip_bf16.h>
#include <math.h>

// BlockwiseDense: y[b,i,j,k] = sum_l quant(relu(cores[i,j,k,l])) * x[b, j*256+l]
// x: (128, 4096) f32, cores: (16,16,256,256) f32, out: (128,16,16,256) f32.
//
// v6: v5 with the staging bug fixed (each thread now stages 16 W elems, the
// full 16x256 tile). Structure:
//   - WG = (i, j, 16 k-rows); grid 4096 -> ~4 generations (tail refill).
//   - ALL global loads (4x f32x4 W + 16x bf16x8 B per thread) issued BEFORE
//     the barrier; the barrier's vmcnt(0) drain leaves them in registers ->
//     MFMA phase is pure LDS+MFMA. asm pins stop re-sinking.
//   - log-space midpoint quantize: one log2 + one exp2, decision frac >= Cf.
//   - x pre-converted to bf16 in d_ws (L2-resident), XOR-swizzled LDS W tile.

typedef __attribute__((ext_vector_type(4))) float f32x4;
typedef __attribute__((ext_vector_type(8))) short bf16x8;  // 8 bf16
typedef __attribute__((ext_vector_type(8))) short s16x8;
typedef __attribute__((ext_vector_type(4))) short s16x4;

#define TAU   0.75f
#define G_INF 2.0f
#define G_MIN 0.001f

__device__ __forceinline__ short f2bf_rne(float f) {
    union { float f; unsigned u; } v; v.f = f;
    unsigned u = v.u;
    return (short)((u + 0x7FFFu + ((u >> 16) & 1u)) >> 16);
}

__device__ __forceinline__ void pin4(f32x4& v) { asm volatile("" : "+v"(v)); }

// ---- kernel 1: x f32 -> bf16 (1 MB, L2-resident thereafter) ----
__global__ __launch_bounds__(256)
void xcvt(const float* __restrict__ xin, short* __restrict__ xbf) {
    int idx = (blockIdx.x * 256 + threadIdx.x) * 8;
    f32x4 a = *(const f32x4*)(xin + idx);
    f32x4 b = *(const f32x4*)(xin + idx + 4);
    s16x8 o;
    o[0] = f2bf_rne(a[0]); o[1] = f2bf_rne(a[1]);
    o[2] = f2bf_rne(a[2]); o[3] = f2bf_rne(a[3]);
    o[4] = f2bf_rne(b[0]); o[5] = f2bf_rne(b[1]);
    o[6] = f2bf_rne(b[2]); o[7] = f2bf_rne(b[3]);
    *(s16x8*)(xbf + idx) = o;
}

// ---- kernel 2: fused quantize + blockwise GEMM ----
template<bool XBF>
__global__ __launch_bounds__(256, 4)
void bd_fused(const float* __restrict__ x,
              const short* __restrict__ xbf,
              const float* __restrict__ cores,
              float* __restrict__ out)
{
    __shared__ unsigned char wq[16 * 512];  // 16 rows x 256 bf16, XOR-swizzled

    const int tid  = threadIdx.x;
    const int wave = tid >> 6;
    const int lane = tid & 63;
    const int l15  = lane & 15;
    const int l4   = lane >> 4;

    const int bid = blockIdx.x;
    const int ns  = bid & 15;         // which 16-k slice
    const int j   = (bid >> 4) & 15;  // input block
    const int i   = bid >> 8;         // output block
    const int k0  = ns * 16;

    // quantization constants (f32, mirroring the numpy level construction)
    const float scale     = (G_INF - G_MIN) / (1.0f - expf(-TAU));
    const float inv_scale = 1.0f / scale;
    const float T0 = 1.0f + G_MIN * inv_scale;                 // t = T0 - w/scale
    const float kn = -(255.0f / TAU) * 0.69314718055994531f;   // n = kn*log2(t)
    const float c2 = -(TAU / 255.0f) * 1.44269504088896341f;   // e_g = exp2(c2*g)
    const float Ac = G_MIN + scale;                            // level = Ac - scale*e_g
    const float rho = expf(-TAU / 255.0f);
    const float Cf  = logf((1.0f + rho) * 0.5f) / logf(rho);   // ~0.49963: frac>=Cf -> up

    // ---- issue W loads: full 16x256 tile, 4x f32x4 per thread ----
    const float* wsrc = cores + (((size_t)(i * 16 + j)) << 16) + ((size_t)k0 << 8);
    f32x4 wv[4];
    #pragma unroll
    for (int it = 0; it < 4; ++it)
        wv[it] = *(const f32x4*)(wsrc + it * 1024 + tid * 4);  // 1KB/wave contiguous

    // ---- issue ALL 16 B loads: latency hides under quantize+barrier ----
    const int brow0 = wave * 32;
    const short* xb = xbf + (size_t)(brow0 + l15) * 4096 + j * 256 + l4 * 8;
    const float* xf = x   + (size_t)(brow0 + l15) * 4096 + j * 256 + l4 * 8;
    bf16x8 bfr[8][2];
    #pragma unroll
    for (int s = 0; s < 8; ++s) {
        #pragma unroll
        for (int mt = 0; mt < 2; ++mt) {
            if (XBF) {
                bfr[s][mt] = *(const bf16x8*)(xb + (size_t)mt * 65536 + s * 32);
            } else {
                const float* p = xf + (size_t)mt * 65536 + s * 32;
                f32x4 v0 = *(const f32x4*)p;
                f32x4 v1 = *(const f32x4*)(p + 4);
                bf16x8 b;
                b[0] = f2bf_rne(v0[0]); b[1] = f2bf_rne(v0[1]);
                b[2] = f2bf_rne(v0[2]); b[3] = f2bf_rne(v0[3]);
                b[4] = f2bf_rne(v1[0]); b[5] = f2bf_rne(v1[1]);
                b[6] = f2bf_rne(v1[2]); b[7] = f2bf_rne(v1[3]);
                bfr[s][mt] = b;
            }
        }
    }

    // ---- quantize 16 W elems, swizzled LDS writes ----
    #pragma unroll
    for (int it = 0; it < 4; ++it) {
        s16x4 q;
        #pragma unroll
        for (int c = 0; c < 4; ++c) {
            float w = fmaxf(wv[it][c], 0.0f);
            float t = fmaf(w, -inv_scale, T0);      // t = exp(-tau*n/255) at w
            t = fmaxf(t, 1e-8f);
            float nr = kn * __log2f(t);             // continuous level index
            nr = fminf(fmaxf(nr, 0.0f), 255.0f);
            float ff = floorf(nr);
            // exact midpoint rule in log-space: levels geometric in t, w<->t
            // affine => nearest-in-w == (frac >= Cf ? up : down).
            float g  = (nr - ff < Cf) ? ff : ff + 1.0f;
            float ef = exp2f(c2 * g);               // v_exp_f32
            float qv = fmaf(ef, -scale, Ac);        // level[g]
            q[c] = f2bf_rne(qv);
        }
        int e   = it * 1024 + tid * 4;       // element index in 16x256 tile
        int r   = e >> 8;                    // local k row, 0..15
        int kb  = (e & 255) * 2;             // byte offset within row
        int off = (r * 512 + kb) ^ ((r & 7) << 4);  // bank swizzle
        *(s16x4*)(wq + off) = q;             // ds_write_b64
    }
    __syncthreads();   // also drains vmcnt(0): all bfr in registers past here

    // keep bfr live here (prevents re-sinking loads into the MFMA loop)
    #pragma unroll
    for (int s = 0; s < 8; ++s) {
        pin4(*(f32x4*)&bfr[s][0]);
        pin4(*(f32x4*)&bfr[s][1]);
    }

    // ---- MFMA: wave = 32 batch rows x 16 k-rows, K=256, pure LDS+MFMA ----
    f32x4 acc[2];
    acc[0] = (f32x4){0.f, 0.f, 0.f, 0.f};
    acc[1] = (f32x4){0.f, 0.f, 0.f, 0.f};

    #pragma unroll
    for (int s = 0; s < 8; ++s) {
        // A-frag (W): lane holds row = k = l15, elems l = 32s + l4*8 + e
        int off = (l15 * 512 + s * 64 + l4 * 16) ^ ((l15 & 7) << 4);
        bf16x8 afr = *(const bf16x8*)(wq + off);   // ds_read_b128, swizzled
        acc[0] = __builtin_amdgcn_mfma_f32_16x16x32_bf16(afr, bfr[s][0], acc[0], 0, 0, 0);
        acc[1] = __builtin_amdgcn_mfma_f32_16x16x32_bf16(afr, bfr[s][1], acc[1], 0, 0, 0);
    }

    // ---- store: D row = l4*4+v = k offset, col = l15 = b offset ----
    #pragma unroll
    for (int mt = 0; mt < 2; ++mt) {
        int b  = brow0 + mt * 16 + l15;
        int kg = k0 + (l4 << 2);
        *(f32x4*)(out + (((size_t)((b * 16 + i) * 16 + j)) << 8) + kg) = acc[mt];
    }
}

extern "C" void kernel_launch(void* const* d_in, const int* in_sizes, int n_in,
                              void* d_out, int out_size, void* d_ws, size_t ws_size,
                              hipStream_t stream) {
    const float* x     = (const float*)d_in[0];
    const float* cores = (const float*)d_in[1];
    float* out = (float*)d_out;

    const size_t xbytes = (size_t)128 * 4096 * sizeof(short);  // 1 MB
    if (ws_size >= xbytes) {
        short* xbf = (short*)d_ws;
        xcvt<<<dim3(256), dim3(256), 0, stream>>>(x, xbf);
        bd_fused<true><<<dim3(4096), dim3(256), 0, stream>>>(x, xbf, cores, out);
    } else {
        bd_fused<false><<<dim3(4096), dim3(256), 0, stream>>>(x, nullptr, cores, out);
    }
}